// Round 16
// baseline (10255.783 us; speedup 1.0000x reference)
//
#include <hip/hip_runtime.h>
#include <math.h>

#define NINP 64
#define NH 512
#define G4 2048   // 4*NH
#define T 64
#define BATCH 2048
#define LDIN 4097 // T*NINP+1
#define XCOLS 4096

typedef _Float16 half8 __attribute__((ext_vector_type(8)));
typedef float f32x4 __attribute__((ext_vector_type(4)));
typedef unsigned short ushort8 __attribute__((ext_vector_type(8)));
typedef unsigned short ushort4v __attribute__((ext_vector_type(4)));

__device__ __forceinline__ float sigmf(float x) { return 1.0f / (1.0f + expf(-x)); }

__device__ __forceinline__ unsigned short f2h_bits(float f) {
    _Float16 h = (_Float16)f;
    return __builtin_bit_cast(unsigned short, h);
}
__device__ __forceinline__ float h_to_f(unsigned short b) {
    return (float)__builtin_bit_cast(_Float16, b);
}

// global -> LDS DMA, 16B per lane. LDS dest = wave-uniform base + lane*16.
__device__ __forceinline__ void gll16(const void* g, void* l) {
    __builtin_amdgcn_global_load_lds(
        (const __attribute__((address_space(1))) unsigned int*)g,
        (__attribute__((address_space(3))) unsigned int*)l, 16, 0, 0);
}

// ---------------------------------------------------------------------------
// R15 diagnosis: LDS port = largest per-tile consumer (88 inst ~ 1050 cyc of
// 1870). A-operand doesn't need LDS (each fragment used by 2 waves only).
// NEW: A (h/x fp16 hi+lo) loaded DIRECTLY global->VGPR as MFMA fragments
// (addresses identical in form to the old LDS reads: group = fg ^ rdsw,
// against the XOR-permuted global layout). W stays DMA->LDS (shared by all
// waves). LDS inst/tile 88 -> 40. LDS block 49KB -> 33.8KB.
// fp16 2-product: C = Ahi*W + Alo*W (bit-identical to R15).
// Geometry: 512 thr / 8 waves (4m x 2n), block tile 128x128, wave 32x64,
// acc[2][4], BK=32. Double-buffered W + A-regs, manual 2-phase unroll
// (NT always even), plain __syncthreads (compiler-managed waits).
// One dispatch per superstep [L2(s-3) | L1(s-2) | P1(s)], 3 blocks/CU.
// Gate columns PERMUTED: n' = j*4+g. 2D XCD partition. t=0: K1=0 + zc.
// ---------------------------------------------------------------------------
#define WBUF 4096   // ushorts per W buffer (8192 B)

struct Job {
    const ushort *A0hi, *A0lo; int lda0;
    const ushort *W0; int K0;
    const ushort *A1hi, *A1lo; int lda1;
    const ushort *W1; int K1;
    const float *bias, *pv, *pc;
    float *c;
    ushort *hhi, *hlo;
    const ushort *ophi, *oplo;
    float *piadst, *odst;
    int ostride, zc;
};

__global__ __launch_bounds__(512, 6) void lstm_fused3_k(
    Job j0, Job j1, Job j2, int nA, int nAB,
    const float* __restrict__ Wl, const float* __restrict__ blv,
    const float* __restrict__ input)
{
    __shared__ __align__(16) ushort smem[16896];   // 33792 B: 2 W bufs aliased under Gs[64][132]
    float* Gs = (float*)smem;

    const int tid = threadIdx.x;
    const int lane = tid & 63;
    const int wid = tid >> 6;        // 0..7

    Job j; int bid;
    if ((int)blockIdx.x < nA)       { j = j0; bid = blockIdx.x; }
    else if ((int)blockIdx.x < nAB) { j = j1; bid = blockIdx.x - nA; }
    else                            { j = j2; bid = blockIdx.x - nAB; }

    // 2D XCD-pinned tile mapping: xcd>>2 = m-half, xcd&3 = n-quarter
    const int xcd = bid & 7;
    const int loc = bid >> 3;                         // 0..31
    const int mblk = ((xcd >> 2) << 3) | (loc & 7);   // 0..15
    const int nblk = ((xcd & 3) << 2) | (loc >> 3);   // 0..15
    const int m0 = mblk * 128;
    const int n0 = nblk * 128;

    // ---- prologue: out-projection of previous h (1 row per wave) ----
    if (j.ophi != nullptr) {
        int row = bid * 8 + wid;
        int xr = (row >> 1) & 3;
        int colp = ((lane >> 2) * 32) + (((lane & 3) ^ xr) << 3);
        ushort8 hh8 = *(const ushort8*)&j.ophi[(size_t)row * NH + colp];
        ushort8 hl8 = *(const ushort8*)&j.oplo[(size_t)row * NH + colp];
        const float4* wv = (const float4*)(Wl + lane * 8);
        float4 w0 = wv[0], w1 = wv[1];
        float wreg[8] = {w0.x, w0.y, w0.z, w0.w, w1.x, w1.y, w1.z, w1.w};
        float s = 0.f;
        #pragma unroll
        for (int e = 0; e < 8; ++e) {
            float h = h_to_f(hh8[e]) + h_to_f(hl8[e]);
            s = fmaf(h, wreg[e], s);
        }
        #pragma unroll
        for (int off = 32; off > 0; off >>= 1) s += __shfl_down(s, off);
        if (lane == 0) {
            float proj = s + blv[0];
            if (j.odst) j.odst[(size_t)row * j.ostride] = proj;
            if (j.piadst) j.piadst[row] = fabsf(proj) * input[(size_t)row * LDIN + (LDIN - 1)];
        }
    }

    // wave geometry: 4m x 2n, wave tile 32x64
    const int wm = wid >> 1;        // 0..3
    const int wn = wid & 1;         // 0..1
    const int fr = lane & 15;
    const int fg = lane >> 4;
    const int rdsw = (fr >> 1) & 3; // swizzle group (row bases multiple of 16)

    // W staging geometry: 512 threads, 1 gll16 each (W tile = 8KB)
    const int srow = tid >> 2;      // 0..127
    const int aslot = tid & 3;

    const int nt0 = j.K0 >> 5;
    const int nt1 = j.K1 >> 5;
    const int NT = nt0 + nt1;       // always even (K multiples of 64; K1=0 at t=0)

    auto stageW = [&](int t, int buf) {
        const ushort* Wp; int K_, kt;
        if (t < nt0) { Wp = j.W0; K_ = j.K0; kt = t * 32; }
        else         { Wp = j.W1; K_ = j.K1; kt = (t - nt0) * 32; }
        char* wb = (char*)smem + buf * 8192 + wid * 1024;
        gll16(&Wp[(size_t)(n0 + srow) * K_ + kt + aslot * 8], wb);
    };

    auto loadA = [&](int t, half8& a0h, half8& a1h, half8& a0l, half8& a1l) {
        const ushort *Ahi, *Alo; int lda_, kt;
        if (t < nt0) { Ahi = j.A0hi; Alo = j.A0lo; lda_ = j.lda0; kt = t * 32; }
        else         { Ahi = j.A1hi; Alo = j.A1lo; lda_ = j.lda1; kt = (t - nt0) * 32; }
        size_t base = (size_t)(m0 + wm * 32 + fr) * lda_ + kt + ((fg ^ rdsw) << 3);
        size_t r16 = (size_t)16 * lda_;
        a0h = *(const half8*)&Ahi[base];
        a1h = *(const half8*)&Ahi[base + r16];
        a0l = *(const half8*)&Alo[base];
        a1l = *(const half8*)&Alo[base + r16];
    };

    f32x4 acc[2][4] = {};

    auto compute = [&](const ushort* bp, half8 a0h, half8 a1h, half8 a0l, half8 a1l) {
        half8 wv[4];
        #pragma unroll
        for (int in = 0; in < 4; ++in) {
            int off = (wn * 64 + in * 16 + fr) * 32 + ((fg ^ rdsw) << 3);
            wv[in] = *(const half8*)&bp[off];
        }
        #pragma unroll
        for (int in = 0; in < 4; ++in) {
            acc[0][in] = __builtin_amdgcn_mfma_f32_16x16x32_f16(a0h, wv[in], acc[0][in], 0, 0, 0);
            acc[1][in] = __builtin_amdgcn_mfma_f32_16x16x32_f16(a1h, wv[in], acc[1][in], 0, 0, 0);
        }
        #pragma unroll
        for (int in = 0; in < 4; ++in) {
            acc[0][in] = __builtin_amdgcn_mfma_f32_16x16x32_f16(a0l, wv[in], acc[0][in], 0, 0, 0);
            acc[1][in] = __builtin_amdgcn_mfma_f32_16x16x32_f16(a1l, wv[in], acc[1][in], 0, 0, 0);
        }
    };

    half8 A0h, A1h, A0l, A1l, B0h, B1h, B0l, B1l;

    stageW(0, 0);
    loadA(0, A0h, A1h, A0l, A1l);

    for (int t = 0; t < NT; t += 2) {
        __syncthreads();                    // W(t) in LDS; A(t) regs landed
        if (t + 1 < NT) { stageW(t + 1, 1); loadA(t + 1, B0h, B1h, B0l, B1l); }
        compute(smem, A0h, A1h, A0l, A1l);
        __syncthreads();                    // buf0 reads done; W(t+1) landed
        if (t + 2 < NT) { stageW(t + 2, 0); loadA(t + 2, A0h, A1h, A0l, A1l); }
        compute(smem + WBUF, B0h, B1h, B0l, B1l);
    }

    // ---- epilogue: 2 chunks (ch = m-fragment), Gs = [64][132] f32 aliased ----
    #pragma unroll
    for (int ch = 0; ch < 2; ++ch) {
        __syncthreads();   // stage-buffer reads (or prev chunk) done
        {
            int g64 = wm * 16 + fg * 4;               // Gs row base
            int rowl = wm * 32 + ch * 16 + fg * 4;    // global row base
            #pragma unroll
            for (int in = 0; in < 4; ++in) {
                int npl = wn * 64 + in * 16 + fr;
                int np = n0 + npl;
                float bias = j.bias[np];
                float pcv = (j.pc != nullptr) ? j.pc[np] : 0.0f;
                #pragma unroll
                for (int r = 0; r < 4; ++r) {
                    float g = acc[ch][in][r] + bias;
                    if (j.pv != nullptr) g += j.pv[m0 + rowl + r] * pcv;
                    Gs[(g64 + r) * 132 + npl] = g;
                }
            }
        }
        __syncthreads();
        {
            int r64 = tid >> 3;                  // 0..63 (Gs row)
            int jq = (tid & 7) * 4;              // j-quad within 32-j block
            int brow = (r64 >> 4) * 32 + ch * 16 + (r64 & 15);
            int jbase = (n0 >> 2) + jq;
            size_t rowb = (size_t)(m0 + brow) * NH;
            size_t idx = rowb + jbase;
            float co[4];
            if (j.zc) {
                co[0] = co[1] = co[2] = co[3] = 0.0f;
            } else {
                float4 c0 = *(const float4*)&j.c[idx];
                co[0] = c0.x; co[1] = c0.y; co[2] = c0.z; co[3] = c0.w;
            }
            float cn[4], hn[4];
            #pragma unroll
            for (int jj = 0; jj < 4; ++jj) {
                float4 gv = *(const float4*)&Gs[r64 * 132 + (jq + jj) * 4];
                float cnv = sigmf(gv.y) * co[jj] + sigmf(gv.x) * tanhf(gv.z);
                cn[jj] = cnv;
                hn[jj] = sigmf(gv.w) * tanhf(cnv);
            }
            float4 cs = {cn[0], cn[1], cn[2], cn[3]};
            *(float4*)&j.c[idx] = cs;
            ushort4v hh, hl;
            #pragma unroll
            for (int e = 0; e < 4; ++e) {
                unsigned short hb = f2h_bits(hn[e]);
                hh[e] = hb;
                hl[e] = f2h_bits(hn[e] - h_to_f(hb));
            }
            int xb = (brow >> 1) & 3;
            int colp = (jbase & ~31) | ((((jbase >> 3) & 3) ^ xb) << 3) | (jbase & 7);
            *(ushort4v*)&j.hhi[rowb + colp] = hh;
            *(ushort4v*)&j.hlo[rowb + colp] = hl;
        }
    }
}

// Standalone out-projection from XOR-permuted fp16 hi/lo h, optional pia.
__global__ __launch_bounds__(256) void out_proj_hl(const ushort* __restrict__ hhi,
                                                   const ushort* __restrict__ hlo,
                                                   const float* __restrict__ Wl,
                                                   const float* __restrict__ blv,
                                                   const float* __restrict__ scaleBase,
                                                   float* __restrict__ piadst,
                                                   float* __restrict__ odst, int ostride)
{
    int wave = threadIdx.x >> 6;
    int lane = threadIdx.x & 63;
    int row = blockIdx.x * 4 + wave;
    int xr = (row >> 1) & 3;
    int colp = ((lane >> 2) * 32) + (((lane & 3) ^ xr) << 3);
    ushort8 hh8 = *(const ushort8*)&hhi[(size_t)row * NH + colp];
    ushort8 hl8 = *(const ushort8*)&hlo[(size_t)row * NH + colp];
    const float4* wv = (const float4*)(Wl + lane * 8);
    float4 w0 = wv[0], w1 = wv[1];
    float wreg[8] = {w0.x, w0.y, w0.z, w0.w, w1.x, w1.y, w1.z, w1.w};
    float s = 0.f;
    #pragma unroll
    for (int e = 0; e < 8; ++e) {
        float h = h_to_f(hh8[e]) + h_to_f(hl8[e]);
        s = fmaf(h, wreg[e], s);
    }
    #pragma unroll
    for (int off = 32; off > 0; off >>= 1) s += __shfl_down(s, off);
    if (lane == 0) {
        float proj = s + blv[0];
        if (odst) odst[(size_t)row * ostride] = proj;
        if (piadst) piadst[row] = fabsf(proj) * scaleBase[(size_t)row * LDIN + (LDIN - 1)];
    }
}

// Split W[4NH][ldw] into permuted SINGLE fp16 plane, n' = j*4+g, with
// XOR-permuted 8-elem groups within each 32-col K-block.
__global__ __launch_bounds__(256) void split_perm_w_k(const float* __restrict__ W,
                                                      ushort* __restrict__ wout,
                                                      int ldw, int kshift)
{
    int idx = blockIdx.x * 256 + threadIdx.x;
    int K = 1 << kshift;
    int np = idx >> kshift;
    int k = idx & (K - 1);
    int ks = (k & ~31) | ((((k >> 3) & 3) ^ ((np >> 1) & 3)) << 3) | (k & 7);
    int orig = ((np & 3) << 9) | (np >> 2);
    wout[idx] = f2h_bits(W[(size_t)orig * ldw + ks]);
}

// Split input x into fp16 hi/lo [b][4096], XOR-permuted groups per 32-block.
__global__ __launch_bounds__(256) void split_x_k(const float* __restrict__ input,
                                                 ushort* __restrict__ xhi,
                                                 ushort* __restrict__ xlo)
{
    int idx = blockIdx.x * 256 + threadIdx.x;   // over BATCH*XCOLS
    int b = idx >> 12;
    int col = idx & (XCOLS - 1);
    int cs = (col & ~31) | ((((col >> 3) & 3) ^ ((b >> 1) & 3)) << 3) | (col & 7);
    float v = input[(size_t)b * LDIN + cs];
    unsigned short hb = f2h_bits(v);
    xhi[idx] = hb;
    xlo[idx] = f2h_bits(v - h_to_f(hb));
}

__global__ __launch_bounds__(256) void bias_prep_k(const float* __restrict__ bih,
                                                   const float* __restrict__ bhh,
                                                   float* __restrict__ bperm)
{
    int np = blockIdx.x * 256 + threadIdx.x;
    int orig = ((np & 3) << 9) | (np >> 2);
    bperm[np] = bih[orig] + bhh[orig];
}

__global__ __launch_bounds__(256) void pc_prep_k(const float* __restrict__ Wih1,
                                                 float* __restrict__ pc)
{
    int np = blockIdx.x * 256 + threadIdx.x;
    int orig = ((np & 3) << 9) | (np >> 2);
    pc[np] = Wih1[(size_t)orig * (NINP + 1) + NINP];
}

extern "C" void kernel_launch(void* const* d_in, const int* in_sizes, int n_in,
                              void* d_out, int out_size, void* d_ws, size_t ws_size,
                              hipStream_t stream)
{
    const float* input = (const float*)d_in[0];
    const float* Wih_p = (const float*)d_in[1];
    const float* Whh_p = (const float*)d_in[2];
    const float* bih_p = (const float*)d_in[3];
    const float* bhh_p = (const float*)d_in[4];
    const float* Wih1  = (const float*)d_in[5];
    const float* Whh1  = (const float*)d_in[6];
    const float* bih1  = (const float*)d_in[7];
    const float* bhh1  = (const float*)d_in[8];
    const float* Wih2  = (const float*)d_in[9];
    const float* Whh2  = (const float*)d_in[10];
    const float* bih2  = (const float*)d_in[11];
    const float* bhh2  = (const float*)d_in[12];
    const float* Wl    = (const float*)d_in[13];
    const float* bl    = (const float*)d_in[14];
    float* out = (float*)d_out;

    const size_t HC = (size_t)BATCH * NH;       // 1M elems
    char* p = (char*)d_ws;
    auto alloc = [&](size_t bytes) { char* r = p; p += (bytes + 255) & ~(size_t)255; return r; };

    float* c_p = (float*)alloc(HC * 4);
    float* c1  = (float*)alloc(HC * 4);
    float* c2  = (float*)alloc(HC * 4);
    ushort* hps_hi[2]; ushort* hps_lo[2];
    ushort* h1s_hi[2]; ushort* h1s_lo[2];
    ushort* h2s_hi[2]; ushort* h2s_lo[2];
    for (int i = 0; i < 2; ++i) { hps_hi[i] = (ushort*)alloc(HC * 2); hps_lo[i] = (ushort*)alloc(HC * 2); }
    for (int i = 0; i < 2; ++i) { h1s_hi[i] = (ushort*)alloc(HC * 2); h1s_lo[i] = (ushort*)alloc(HC * 2); }
    for (int i = 0; i < 2; ++i) { h2s_hi[i] = (ushort*)alloc(HC * 2); h2s_lo[i] = (ushort*)alloc(HC * 2); }
    float* pias   = (float*)alloc((size_t)T * BATCH * 4);
    ushort* WhhP_h = (ushort*)alloc((size_t)G4 * NH * 2);
    ushort* WihP_h = (ushort*)alloc((size_t)G4 * NINP * 2);
    ushort* Whh1_h = (ushort*)alloc((size_t)G4 * NH * 2);
    ushort* Wih1x_h = (ushort*)alloc((size_t)G4 * NINP * 2);
    ushort* Wih2_h = (ushort*)alloc((size_t)G4 * NH * 2);
    ushort* Whh2_h = (ushort*)alloc((size_t)G4 * NH * 2);
    ushort* xhi = (ushort*)alloc((size_t)BATCH * XCOLS * 2);
    ushort* xlo = (ushort*)alloc((size_t)BATCH * XCOLS * 2);
    float* biasP = (float*)alloc(G4 * 4);
    float* bias1 = (float*)alloc(G4 * 4);
    float* bias2 = (float*)alloc(G4 * 4);
    float* pc1   = (float*)alloc(G4 * 4);

    // prep (no memset: t=0 jobs skip h-segments via K=0 and zero c via zc)
    split_perm_w_k<<<(G4 * NH) / 256, 256, 0, stream>>>(Whh_p, WhhP_h, NH, 9);
    split_perm_w_k<<<(G4 * NINP) / 256, 256, 0, stream>>>(Wih_p, WihP_h, NINP, 6);
    split_perm_w_k<<<(G4 * NH) / 256, 256, 0, stream>>>(Whh1, Whh1_h, NH, 9);
    split_perm_w_k<<<(G4 * NINP) / 256, 256, 0, stream>>>(Wih1, Wih1x_h, NINP + 1, 6);
    split_perm_w_k<<<(G4 * NH) / 256, 256, 0, stream>>>(Wih2, Wih2_h, NH, 9);
    split_perm_w_k<<<(G4 * NH) / 256, 256, 0, stream>>>(Whh2, Whh2_h, NH, 9);
    split_x_k<<<(BATCH * XCOLS) / 256, 256, 0, stream>>>(input, xhi, xlo);
    bias_prep_k<<<G4 / 256, 256, 0, stream>>>(bih_p, bhh_p, biasP);
    bias_prep_k<<<G4 / 256, 256, 0, stream>>>(bih1, bhh1, bias1);
    bias_prep_k<<<G4 / 256, 256, 0, stream>>>(bih2, bhh2, bias2);
    pc_prep_k<<<G4 / 256, 256, 0, stream>>>(Wih1, pc1);

    auto jobP1 = [&](int s) {
        Job jo = {};
        jo.A0hi = xhi + (size_t)s * NINP; jo.A0lo = xlo + (size_t)s * NINP; jo.lda0 = XCOLS;
        jo.W0 = WihP_h; jo.K0 = NINP;
        jo.A1hi = hps_hi[s & 1]; jo.A1lo = hps_lo[s & 1]; jo.lda1 = NH;
        jo.W1 = WhhP_h; jo.K1 = (s == 0) ? 0 : NH;
        jo.bias = biasP; jo.pv = nullptr; jo.pc = nullptr;
        jo.c = c_p; jo.hhi = hps_hi[(s + 1) & 1]; jo.hlo = hps_lo[(s + 1) & 1];
        jo.ophi = (s > 0) ? hps_hi[s & 1] : nullptr; jo.oplo = hps_lo[s & 1];
        jo.piadst = (s > 0) ? (pias + (size_t)(s - 1) * BATCH) : nullptr;
        jo.odst = nullptr; jo.ostride = 0; jo.zc = (s == 0);
        return jo;
    };
    auto jobL1 = [&](int t) {
        Job jo = {};
        jo.A0hi = xhi + (size_t)t * NINP; jo.A0lo = xlo + (size_t)t * NINP; jo.lda0 = XCOLS;
        jo.W0 = Wih1x_h; jo.K0 = NINP;
        jo.A1hi = h1s_hi[t & 1]; jo.A1lo = h1s_lo[t & 1]; jo.lda1 = NH;
        jo.W1 = Whh1_h; jo.K1 = (t == 0) ? 0 : NH;
        jo.bias = bias1; jo.pv = pias + (size_t)t * BATCH; jo.pc = pc1;
        jo.c = c1; jo.hhi = h1s_hi[(t + 1) & 1]; jo.hlo = h1s_lo[(t + 1) & 1];
        jo.ophi = nullptr; jo.oplo = nullptr;
        jo.piadst = nullptr; jo.odst = nullptr; jo.ostride = 0;
        jo.zc = (t == 0);
        return jo;
    };
    auto jobL2 = [&](int t) {
        Job jo = {};
        jo.A0hi = h1s_hi[(t + 1) & 1]; jo.A0lo = h1s_lo[(t + 1) & 1]; jo.lda0 = NH;
        jo.W0 = Wih2_h; jo.K0 = NH;
        jo.A1hi = h2s_hi[t & 1]; jo.A1lo = h2s_lo[t & 1]; jo.lda1 = NH;
        jo.W1 = Whh2_h; jo.K1 = (t == 0) ? 0 : NH;
        jo.bias = bias2; jo.pv = nullptr; jo.pc = nullptr;
        jo.c = c2; jo.hhi = h2s_hi[(t + 1) & 1]; jo.hlo = h2s_lo[(t + 1) & 1];
        jo.ophi = (t > 0) ? h2s_hi[t & 1] : nullptr; jo.oplo = h2s_lo[t & 1];
        jo.piadst = nullptr;
        jo.odst = (t > 0) ? (out + (t - 1)) : nullptr; jo.ostride = T + 1;
        jo.zc = (t == 0);
        return jo;
    };

    // One dispatch per superstep s: [L2(s-3) | L1(s-2) | P1(s)], 3 blocks/CU.
    for (int s = 0; s <= 66; ++s) {
        int nL2 = (s >= 3) ? 256 : 0;
        int nL1 = (s >= 2 && s <= 65) ? 256 : 0;
        int nP1 = (s <= 63) ? 256 : 0;
        Job j0 = {}, j1 = {}, j2 = {};
        if (nL2) j0 = jobL2(s - 3);
        if (nL1) j1 = jobL1(s - 2);
        if (nP1) j2 = jobP1(s);
        int nA = nL2, nAB = nL2 + nL1, total = nL2 + nL1 + nP1;
        lstm_fused3_k<<<total, 512, 0, stream>>>(j0, j1, j2, nA, nAB, Wl, bl, input);
        if (s == 63) {
            // T1: h_p(64) ready -> pias[63] (used by L1(63) at s=65) and raw
            // last_pia column out[:,T].
            out_proj_hl<<<BATCH / 4, 256, 0, stream>>>(hps_hi[0], hps_lo[0], Wl, bl,
                                                       input, pias + (size_t)63 * BATCH,
                                                       out + T, T + 1);
        }
    }
    // T4: proj h2(64) -> out[:,63].
    out_proj_hl<<<BATCH / 4, 256, 0, stream>>>(h2s_hi[0], h2s_lo[0], Wl, bl, input,
                                               nullptr, out + 63, T + 1);
}

// Round 17
// 2742.090 us; speedup vs baseline: 3.7401x; 3.7401x over previous
//
#include <hip/hip_runtime.h>
#include <math.h>

#define NINP 64
#define NH 512
#define G4 2048   // 4*NH
#define T 64
#define BATCH 2048
#define LDIN 4097 // T*NINP+1
#define XCOLS 4096

typedef _Float16 half8 __attribute__((ext_vector_type(8)));
typedef float f32x4 __attribute__((ext_vector_type(4)));
typedef unsigned short ushort8 __attribute__((ext_vector_type(8)));
typedef unsigned short ushort4v __attribute__((ext_vector_type(4)));

// fast transcendentals: v_exp_f32 + v_rcp_f32 (sat-safe at +-inf)
__device__ __forceinline__ float sigmf(float x) {
    return __builtin_amdgcn_rcpf(1.0f + __expf(-x));
}
__device__ __forceinline__ float tanhf_fast(float x) {
    return fmaf(-2.0f, __builtin_amdgcn_rcpf(1.0f + __expf(2.0f * x)), 1.0f);
}

__device__ __forceinline__ unsigned short f2h_bits(float f) {
    _Float16 h = (_Float16)f;
    return __builtin_bit_cast(unsigned short, h);
}
__device__ __forceinline__ float h_to_f(unsigned short b) {
    return (float)__builtin_bit_cast(_Float16, b);
}

// global -> LDS DMA, 16B per lane. LDS dest = wave-uniform base + lane*16.
__device__ __forceinline__ void gll16(const void* g, void* l) {
    __builtin_amdgcn_global_load_lds(
        (const __attribute__((address_space(1))) unsigned int*)g,
        (__attribute__((address_space(3))) unsigned int*)l, 16, 0, 0);
}

// ---------------------------------------------------------------------------
// R15 structure (best verified: 2.99ms) + HW transcendentals (R16's A-direct
// regressed: uncoalesced per-lane fragment loads 4x overfetch + scratch spill).
// fp16 2-product scheme: A = fp16 hi+lo, W = single fp16; C = Ahi*W + Alo*W.
// Geometry: 512 thr / 8 waves (4m x 2n), block tile 128x128, wave 32x64,
// acc[2][4], BK=32. LDS: 2 x 24KB stage bufs (Ahi/Alo/W); epilogue
// Gs = [64][132] f32 x 2 chunks, aliased. 49152B -> 3 blocks/CU.
// One dispatch per superstep [L2(s-3) | L1(s-2) | P1(s)], all co-resident.
// XOR swizzle baked into global layout (conflicts==0). vmcnt(3) pipeline.
// Gate columns PERMUTED: n' = j*4+g. 2D XCD partition. t=0: K1=0 + zc.
// ---------------------------------------------------------------------------
#define OFF_ALO 4096
#define OFF_W   8192
#define BUFSZ   12288   // ushorts per buffer (24576 B)

struct Job {
    const ushort *A0hi, *A0lo; int lda0;
    const ushort *W0; int K0;
    const ushort *A1hi, *A1lo; int lda1;
    const ushort *W1; int K1;
    const float *bias, *pv, *pc;
    float *c;
    ushort *hhi, *hlo;
    const ushort *ophi, *oplo;
    float *piadst, *odst;
    int ostride, zc;
};

__global__ __launch_bounds__(512, 6) void lstm_fused3_k(
    Job j0, Job j1, Job j2, int nA, int nAB,
    const float* __restrict__ Wl, const float* __restrict__ blv,
    const float* __restrict__ input)
{
    __shared__ __align__(16) ushort smem[2 * BUFSZ];   // 49152 B
    float* Gs = (float*)smem;                          // [64][132] chunk, aliased

    const int tid = threadIdx.x;
    const int lane = tid & 63;
    const int wid = tid >> 6;        // 0..7

    Job j; int bid;
    if ((int)blockIdx.x < nA)       { j = j0; bid = blockIdx.x; }
    else if ((int)blockIdx.x < nAB) { j = j1; bid = blockIdx.x - nA; }
    else                            { j = j2; bid = blockIdx.x - nAB; }

    // 2D XCD-pinned tile mapping: xcd>>2 = m-half, xcd&3 = n-quarter
    const int xcd = bid & 7;
    const int loc = bid >> 3;                         // 0..31
    const int mblk = ((xcd >> 2) << 3) | (loc & 7);   // 0..15
    const int nblk = ((xcd & 3) << 2) | (loc >> 3);   // 0..15
    const int m0 = mblk * 128;
    const int n0 = nblk * 128;

    // ---- prologue: out-projection of previous h (1 row per wave) ----
    if (j.ophi != nullptr) {
        int row = bid * 8 + wid;
        int xr = (row >> 1) & 3;
        int colp = ((lane >> 2) * 32) + (((lane & 3) ^ xr) << 3);
        ushort8 hh8 = *(const ushort8*)&j.ophi[(size_t)row * NH + colp];
        ushort8 hl8 = *(const ushort8*)&j.oplo[(size_t)row * NH + colp];
        const float4* wv = (const float4*)(Wl + lane * 8);
        float4 w0 = wv[0], w1 = wv[1];
        float wreg[8] = {w0.x, w0.y, w0.z, w0.w, w1.x, w1.y, w1.z, w1.w};
        float s = 0.f;
        #pragma unroll
        for (int e = 0; e < 8; ++e) {
            float h = h_to_f(hh8[e]) + h_to_f(hl8[e]);
            s = fmaf(h, wreg[e], s);
        }
        #pragma unroll
        for (int off = 32; off > 0; off >>= 1) s += __shfl_down(s, off);
        if (lane == 0) {
            float proj = s + blv[0];
            if (j.odst) j.odst[(size_t)row * j.ostride] = proj;
            if (j.piadst) j.piadst[row] = fabsf(proj) * input[(size_t)row * LDIN + (LDIN - 1)];
        }
    }

    // wave geometry: 4m x 2n, wave tile 32x64
    const int wm = wid >> 1;        // 0..3
    const int wn = wid & 1;         // 0..1
    const int fr = lane & 15;
    const int fg = lane >> 4;
    const int rdsw = (fr >> 1) & 3; // read swizzle (row bases multiple of 16)

    // staging geometry: 512 threads, 1 gll16 per plane (Ahi, Alo, W)
    const int srow = tid >> 2;      // 0..127
    const int aslot = tid & 3;

    const int nt0 = j.K0 >> 5;
    const int nt1 = j.K1 >> 5;
    const int NT = nt0 + nt1;

    auto stage = [&](int t, int buf) {
        const ushort *Ahi, *Alo, *Wp;
        int lda_, K_, kt;
        if (t < nt0) { Ahi = j.A0hi; Alo = j.A0lo; lda_ = j.lda0; K_ = j.K0; kt = t * 32; Wp = j.W0; }
        else         { Ahi = j.A1hi; Alo = j.A1lo; lda_ = j.lda1; K_ = j.K1; kt = (t - nt0) * 32; Wp = j.W1; }
        char* wb = (char*)smem + buf * 24576 + wid * 1024;
        const size_t acol = (size_t)kt + aslot * 8;
        gll16(&Ahi[(size_t)(m0 + srow) * lda_ + acol], wb);
        gll16(&Alo[(size_t)(m0 + srow) * lda_ + acol], wb + 8192);
        gll16(&Wp[(size_t)(n0 + srow) * K_ + acol],    wb + 16384);
    };

    f32x4 acc[2][4] = {};
    int cur = 0;

    stage(0, 0);
    if (NT > 1) stage(1, 1);

    for (int t = 0; t < NT; ++t) {
        // counted wait: all but the newest 3 loads (stage t+1)
        if (t + 1 < NT) { asm volatile("s_waitcnt vmcnt(3)" ::: "memory"); }
        else            { asm volatile("s_waitcnt vmcnt(0)" ::: "memory"); }
        __builtin_amdgcn_s_barrier();

        const ushort* bp = smem + cur * BUFSZ;
        half8 ah[2], al[2], wv[4];
        #pragma unroll
        for (int im = 0; im < 2; ++im) {
            int off = (wm * 32 + im * 16 + fr) * 32 + ((fg ^ rdsw) << 3);
            ah[im] = *(const half8*)&bp[off];
            al[im] = *(const half8*)&bp[OFF_ALO + off];
        }
        #pragma unroll
        for (int in = 0; in < 4; ++in) {
            int off = (wn * 64 + in * 16 + fr) * 32 + ((fg ^ rdsw) << 3);
            wv[in] = *(const half8*)&bp[OFF_W + off];
        }
        #pragma unroll
        for (int im = 0; im < 2; ++im)
            #pragma unroll
            for (int in = 0; in < 4; ++in)
                acc[im][in] = __builtin_amdgcn_mfma_f32_16x16x32_f16(ah[im], wv[in], acc[im][in], 0, 0, 0);
        #pragma unroll
        for (int im = 0; im < 2; ++im)
            #pragma unroll
            for (int in = 0; in < 4; ++in)
                acc[im][in] = __builtin_amdgcn_mfma_f32_16x16x32_f16(al[im], wv[in], acc[im][in], 0, 0, 0);

        asm volatile("" ::: "memory");
        __builtin_amdgcn_s_barrier();       // all waves done reading buf[cur]
        asm volatile("" ::: "memory");
        if (t + 2 < NT) stage(t + 2, cur);  // refill the buffer just consumed
        cur ^= 1;
    }

    // ---- epilogue: 2 chunks (im = 0,1), Gs = [64][132] f32 aliased ----
    #pragma unroll
    for (int ch = 0; ch < 2; ++ch) {
        __syncthreads();   // stage-buffer reads (or prev chunk) done
        // stage 1: bias + pia, fragments of chunk ch -> Gs
        {
            int g64 = wm * 16 + fg * 4;               // Gs row base
            int rowl = wm * 32 + ch * 16 + fg * 4;    // global row base
            #pragma unroll
            for (int in = 0; in < 4; ++in) {
                int npl = wn * 64 + in * 16 + fr;
                int np = n0 + npl;
                float bias = j.bias[np];
                float pcv = (j.pc != nullptr) ? j.pc[np] : 0.0f;
                #pragma unroll
                for (int r = 0; r < 4; ++r) {
                    float g = acc[ch][in][r] + bias;
                    if (j.pv != nullptr) g += j.pv[m0 + rowl + r] * pcv;
                    Gs[(g64 + r) * 132 + npl] = g;
                }
            }
        }
        __syncthreads();
        // stage 2: per-cell update (4 cells/thread), coalesced I/O
        {
            int r64 = tid >> 3;                  // 0..63 (Gs row)
            int jq = (tid & 7) * 4;              // j-quad within 32-j block
            int brow = (r64 >> 4) * 32 + ch * 16 + (r64 & 15);
            int jbase = (n0 >> 2) + jq;
            size_t rowb = (size_t)(m0 + brow) * NH;
            size_t idx = rowb + jbase;
            float co[4];
            if (j.zc) {
                co[0] = co[1] = co[2] = co[3] = 0.0f;
            } else {
                float4 c0 = *(const float4*)&j.c[idx];
                co[0] = c0.x; co[1] = c0.y; co[2] = c0.z; co[3] = c0.w;
            }
            float cn[4], hn[4];
            #pragma unroll
            for (int jj = 0; jj < 4; ++jj) {
                float4 gv = *(const float4*)&Gs[r64 * 132 + (jq + jj) * 4];
                float cnv = sigmf(gv.y) * co[jj] + sigmf(gv.x) * tanhf_fast(gv.z);
                cn[jj] = cnv;
                hn[jj] = sigmf(gv.w) * tanhf_fast(cnv);
            }
            float4 cs = {cn[0], cn[1], cn[2], cn[3]};
            *(float4*)&j.c[idx] = cs;
            ushort4v hh, hl;
            #pragma unroll
            for (int e = 0; e < 4; ++e) {
                unsigned short hb = f2h_bits(hn[e]);
                hh[e] = hb;
                hl[e] = f2h_bits(hn[e] - h_to_f(hb));
            }
            int xb = (brow >> 1) & 3;
            int colp = (jbase & ~31) | ((((jbase >> 3) & 3) ^ xb) << 3) | (jbase & 7);
            *(ushort4v*)&j.hhi[rowb + colp] = hh;
            *(ushort4v*)&j.hlo[rowb + colp] = hl;
        }
    }
}

// Standalone out-projection from XOR-permuted fp16 hi/lo h, optional pia.
__global__ __launch_bounds__(256) void out_proj_hl(const ushort* __restrict__ hhi,
                                                   const ushort* __restrict__ hlo,
                                                   const float* __restrict__ Wl,
                                                   const float* __restrict__ blv,
                                                   const float* __restrict__ scaleBase,
                                                   float* __restrict__ piadst,
                                                   float* __restrict__ odst, int ostride)
{
    int wave = threadIdx.x >> 6;
    int lane = threadIdx.x & 63;
    int row = blockIdx.x * 4 + wave;
    int xr = (row >> 1) & 3;
    int colp = ((lane >> 2) * 32) + (((lane & 3) ^ xr) << 3);
    ushort8 hh8 = *(const ushort8*)&hhi[(size_t)row * NH + colp];
    ushort8 hl8 = *(const ushort8*)&hlo[(size_t)row * NH + colp];
    const float4* wv = (const float4*)(Wl + lane * 8);
    float4 w0 = wv[0], w1 = wv[1];
    float wreg[8] = {w0.x, w0.y, w0.z, w0.w, w1.x, w1.y, w1.z, w1.w};
    float s = 0.f;
    #pragma unroll
    for (int e = 0; e < 8; ++e) {
        float h = h_to_f(hh8[e]) + h_to_f(hl8[e]);
        s = fmaf(h, wreg[e], s);
    }
    #pragma unroll
    for (int off = 32; off > 0; off >>= 1) s += __shfl_down(s, off);
    if (lane == 0) {
        float proj = s + blv[0];
        if (odst) odst[(size_t)row * ostride] = proj;
        if (piadst) piadst[row] = fabsf(proj) * scaleBase[(size_t)row * LDIN + (LDIN - 1)];
    }
}

// Split W[4NH][ldw] into permuted SINGLE fp16 plane, n' = j*4+g, with
// XOR-permuted 8-elem groups within each 32-col K-block.
__global__ __launch_bounds__(256) void split_perm_w_k(const float* __restrict__ W,
                                                      ushort* __restrict__ wout,
                                                      int ldw, int kshift)
{
    int idx = blockIdx.x * 256 + threadIdx.x;
    int K = 1 << kshift;
    int np = idx >> kshift;
    int k = idx & (K - 1);
    int ks = (k & ~31) | ((((k >> 3) & 3) ^ ((np >> 1) & 3)) << 3) | (k & 7);
    int orig = ((np & 3) << 9) | (np >> 2);
    wout[idx] = f2h_bits(W[(size_t)orig * ldw + ks]);
}

// Split input x into fp16 hi/lo [b][4096], XOR-permuted groups per 32-block.
__global__ __launch_bounds__(256) void split_x_k(const float* __restrict__ input,
                                                 ushort* __restrict__ xhi,
                                                 ushort* __restrict__ xlo)
{
    int idx = blockIdx.x * 256 + threadIdx.x;   // over BATCH*XCOLS
    int b = idx >> 12;
    int col = idx & (XCOLS - 1);
    int cs = (col & ~31) | ((((col >> 3) & 3) ^ ((b >> 1) & 3)) << 3) | (col & 7);
    float v = input[(size_t)b * LDIN + cs];
    unsigned short hb = f2h_bits(v);
    xhi[idx] = hb;
    xlo[idx] = f2h_bits(v - h_to_f(hb));
}

__global__ __launch_bounds__(256) void bias_prep_k(const float* __restrict__ bih,
                                                   const float* __restrict__ bhh,
                                                   float* __restrict__ bperm)
{
    int np = blockIdx.x * 256 + threadIdx.x;
    int orig = ((np & 3) << 9) | (np >> 2);
    bperm[np] = bih[orig] + bhh[orig];
}

__global__ __launch_bounds__(256) void pc_prep_k(const float* __restrict__ Wih1,
                                                 float* __restrict__ pc)
{
    int np = blockIdx.x * 256 + threadIdx.x;
    int orig = ((np & 3) << 9) | (np >> 2);
    pc[np] = Wih1[(size_t)orig * (NINP + 1) + NINP];
}

extern "C" void kernel_launch(void* const* d_in, const int* in_sizes, int n_in,
                              void* d_out, int out_size, void* d_ws, size_t ws_size,
                              hipStream_t stream)
{
    const float* input = (const float*)d_in[0];
    const float* Wih_p = (const float*)d_in[1];
    const float* Whh_p = (const float*)d_in[2];
    const float* bih_p = (const float*)d_in[3];
    const float* bhh_p = (const float*)d_in[4];
    const float* Wih1  = (const float*)d_in[5];
    const float* Whh1  = (const float*)d_in[6];
    const float* bih1  = (const float*)d_in[7];
    const float* bhh1  = (const float*)d_in[8];
    const float* Wih2  = (const float*)d_in[9];
    const float* Whh2  = (const float*)d_in[10];
    const float* bih2  = (const float*)d_in[11];
    const float* bhh2  = (const float*)d_in[12];
    const float* Wl    = (const float*)d_in[13];
    const float* bl    = (const float*)d_in[14];
    float* out = (float*)d_out;

    const size_t HC = (size_t)BATCH * NH;       // 1M elems
    char* p = (char*)d_ws;
    auto alloc = [&](size_t bytes) { char* r = p; p += (bytes + 255) & ~(size_t)255; return r; };

    float* c_p = (float*)alloc(HC * 4);
    float* c1  = (float*)alloc(HC * 4);
    float* c2  = (float*)alloc(HC * 4);
    ushort* hps_hi[2]; ushort* hps_lo[2];
    ushort* h1s_hi[2]; ushort* h1s_lo[2];
    ushort* h2s_hi[2]; ushort* h2s_lo[2];
    for (int i = 0; i < 2; ++i) { hps_hi[i] = (ushort*)alloc(HC * 2); hps_lo[i] = (ushort*)alloc(HC * 2); }
    for (int i = 0; i < 2; ++i) { h1s_hi[i] = (ushort*)alloc(HC * 2); h1s_lo[i] = (ushort*)alloc(HC * 2); }
    for (int i = 0; i < 2; ++i) { h2s_hi[i] = (ushort*)alloc(HC * 2); h2s_lo[i] = (ushort*)alloc(HC * 2); }
    float* pias   = (float*)alloc((size_t)T * BATCH * 4);
    ushort* WhhP_h = (ushort*)alloc((size_t)G4 * NH * 2);
    ushort* WihP_h = (ushort*)alloc((size_t)G4 * NINP * 2);
    ushort* Whh1_h = (ushort*)alloc((size_t)G4 * NH * 2);
    ushort* Wih1x_h = (ushort*)alloc((size_t)G4 * NINP * 2);
    ushort* Wih2_h = (ushort*)alloc((size_t)G4 * NH * 2);
    ushort* Whh2_h = (ushort*)alloc((size_t)G4 * NH * 2);
    ushort* xhi = (ushort*)alloc((size_t)BATCH * XCOLS * 2);
    ushort* xlo = (ushort*)alloc((size_t)BATCH * XCOLS * 2);
    float* biasP = (float*)alloc(G4 * 4);
    float* bias1 = (float*)alloc(G4 * 4);
    float* bias2 = (float*)alloc(G4 * 4);
    float* pc1   = (float*)alloc(G4 * 4);

    // prep (no memset: t=0 jobs skip h-segments via K=0 and zero c via zc)
    split_perm_w_k<<<(G4 * NH) / 256, 256, 0, stream>>>(Whh_p, WhhP_h, NH, 9);
    split_perm_w_k<<<(G4 * NINP) / 256, 256, 0, stream>>>(Wih_p, WihP_h, NINP, 6);
    split_perm_w_k<<<(G4 * NH) / 256, 256, 0, stream>>>(Whh1, Whh1_h, NH, 9);
    split_perm_w_k<<<(G4 * NINP) / 256, 256, 0, stream>>>(Wih1, Wih1x_h, NINP + 1, 6);
    split_perm_w_k<<<(G4 * NH) / 256, 256, 0, stream>>>(Wih2, Wih2_h, NH, 9);
    split_perm_w_k<<<(G4 * NH) / 256, 256, 0, stream>>>(Whh2, Whh2_h, NH, 9);
    split_x_k<<<(BATCH * XCOLS) / 256, 256, 0, stream>>>(input, xhi, xlo);
    bias_prep_k<<<G4 / 256, 256, 0, stream>>>(bih_p, bhh_p, biasP);
    bias_prep_k<<<G4 / 256, 256, 0, stream>>>(bih1, bhh1, bias1);
    bias_prep_k<<<G4 / 256, 256, 0, stream>>>(bih2, bhh2, bias2);
    pc_prep_k<<<G4 / 256, 256, 0, stream>>>(Wih1, pc1);

    auto jobP1 = [&](int s) {
        Job jo = {};
        jo.A0hi = xhi + (size_t)s * NINP; jo.A0lo = xlo + (size_t)s * NINP; jo.lda0 = XCOLS;
        jo.W0 = WihP_h; jo.K0 = NINP;
        jo.A1hi = hps_hi[s & 1]; jo.A1lo = hps_lo[s & 1]; jo.lda1 = NH;
        jo.W1 = WhhP_h; jo.K1 = (s == 0) ? 0 : NH;
        jo.bias = biasP; jo.pv = nullptr; jo.pc = nullptr;
        jo.c = c_p; jo.hhi = hps_hi[(s + 1) & 1]; jo.hlo = hps_lo[(s + 1) & 1];
        jo.ophi = (s > 0) ? hps_hi[s & 1] : nullptr; jo.oplo = hps_lo[s & 1];
        jo.piadst = (s > 0) ? (pias + (size_t)(s - 1) * BATCH) : nullptr;
        jo.odst = nullptr; jo.ostride = 0; jo.zc = (s == 0);
        return jo;
    };
    auto jobL1 = [&](int t) {
        Job jo = {};
        jo.A0hi = xhi + (size_t)t * NINP; jo.A0lo = xlo + (size_t)t * NINP; jo.lda0 = XCOLS;
        jo.W0 = Wih1x_h; jo.K0 = NINP;
        jo.A1hi = h1s_hi[t & 1]; jo.A1lo = h1s_lo[t & 1]; jo.lda1 = NH;
        jo.W1 = Whh1_h; jo.K1 = (t == 0) ? 0 : NH;
        jo.bias = bias1; jo.pv = pias + (size_t)t * BATCH; jo.pc = pc1;
        jo.c = c1; jo.hhi = h1s_hi[(t + 1) & 1]; jo.hlo = h1s_lo[(t + 1) & 1];
        jo.ophi = nullptr; jo.oplo = nullptr;
        jo.piadst = nullptr; jo.odst = nullptr; jo.ostride = 0;
        jo.zc = (t == 0);
        return jo;
    };
    auto jobL2 = [&](int t) {
        Job jo = {};
        jo.A0hi = h1s_hi[(t + 1) & 1]; jo.A0lo = h1s_lo[(t + 1) & 1]; jo.lda0 = NH;
        jo.W0 = Wih2_h; jo.K0 = NH;
        jo.A1hi = h2s_hi[t & 1]; jo.A1lo = h2s_lo[t & 1]; jo.lda1 = NH;
        jo.W1 = Whh2_h; jo.K1 = (t == 0) ? 0 : NH;
        jo.bias = bias2; jo.pv = nullptr; jo.pc = nullptr;
        jo.c = c2; jo.hhi = h2s_hi[(t + 1) & 1]; jo.hlo = h2s_lo[(t + 1) & 1];
        jo.ophi = (t > 0) ? h2s_hi[t & 1] : nullptr; jo.oplo = h2s_lo[t & 1];
        jo.piadst = nullptr;
        jo.odst = (t > 0) ? (out + (t - 1)) : nullptr; jo.ostride = T + 1;
        jo.zc = (t == 0);
        return jo;
    };

    // One dispatch per superstep s: [L2(s-3) | L1(s-2) | P1(s)], 3 blocks/CU.
    for (int s = 0; s <= 66; ++s) {
        int nL2 = (s >= 3) ? 256 : 0;
        int nL1 = (s >= 2 && s <= 65) ? 256 : 0;
        int nP1 = (s <= 63) ? 256 : 0;
        Job j0 = {}, j1 = {}, j2 = {};
        if (nL2) j0 = jobL2(s - 3);
        if (nL1) j1 = jobL1(s - 2);
        if (nP1) j2 = jobP1(s);
        int nA = nL2, nAB = nL2 + nL1, total = nL2 + nL1 + nP1;
        lstm_fused3_k<<<total, 512, 0, stream>>>(j0, j1, j2, nA, nAB, Wl, bl, input);
        if (s == 63) {
            // T1: h_p(64) ready -> pias[63] (used by L1(63) at s=65) and raw
            // last_pia column out[:,T].
            out_proj_hl<<<BATCH / 4, 256, 0, stream>>>(hps_hi[0], hps_lo[0], Wl, bl,
                                                       input, pias + (size_t)63 * BATCH,
                                                       out + T, T + 1);
        }
    }
    // T4: proj h2(64) -> out[:,63].
    out_proj_hl<<<BATCH / 4, 256, 0, stream>>>(h2s_hi[0], h2s_lo[0], Wl, bl, input,
                                               nullptr, out + 63, T + 1);
}

// Round 18
// 1892.684 us; speedup vs baseline: 5.4186x; 1.4488x over previous
//
#include <hip/hip_runtime.h>
#include <math.h>

#define NINP 64
#define NH 512
#define G4 2048   // 4*NH
#define T 64
#define BATCH 2048
#define LDIN 4097 // T*NINP+1
#define XCOLS 4096

typedef _Float16 half8 __attribute__((ext_vector_type(8)));
typedef float f32x4 __attribute__((ext_vector_type(4)));
typedef unsigned short ushort8 __attribute__((ext_vector_type(8)));
typedef unsigned short ushort4v __attribute__((ext_vector_type(4)));

// fast transcendentals: v_exp_f32 + v_rcp_f32 (sat-safe at +-inf)
__device__ __forceinline__ float sigmf(float x) {
    return __builtin_amdgcn_rcpf(1.0f + __expf(-x));
}
__device__ __forceinline__ float tanhf_fast(float x) {
    return fmaf(-2.0f, __builtin_amdgcn_rcpf(1.0f + __expf(2.0f * x)), 1.0f);
}

__device__ __forceinline__ unsigned short f2h_bits(float f) {
    _Float16 h = (_Float16)f;
    return __builtin_bit_cast(unsigned short, h);
}
__device__ __forceinline__ float h_to_f(unsigned short b) {
    return (float)__builtin_bit_cast(_Float16, b);
}

// global -> LDS DMA, 16B per lane. LDS dest = wave-uniform base + lane*16.
__device__ __forceinline__ void gll16(const void* g, void* l) {
    __builtin_amdgcn_global_load_lds(
        (const __attribute__((address_space(1))) unsigned int*)g,
        (__attribute__((address_space(3))) unsigned int*)l, 16, 0, 0);
}

// ---------------------------------------------------------------------------
// R17 structure + SINGLE-fp16 A (error budget: R17 absmax 4.88e-4 of 2.675e-3
// was W-truncation-dominated; adding A at fp16 predicts ~1e-3, still <2.7e-3).
// C = A*W, ONE MFMA pass (was 2). Staged planes 3 -> 2 (A, W).
// Geometry: 512 thr / 8 waves (4m x 2n), block tile 128x128, wave 32x64,
// acc[2][4], BK=32. LDS: 2 x 16KB stage bufs aliased under Gs[64][132]
// (33792 B total) -> 3+ blocks/CU.
// One dispatch per superstep [L2(s-3) | L1(s-2) | P1(s)], all co-resident.
// XOR swizzle baked into global layout (conflicts==0). vmcnt(2) pipeline.
// Gate columns PERMUTED: n' = j*4+g. 2D XCD partition. t=0: K1=0 + zc.
// HW transcendentals in epilogue (R17, verified).
// ---------------------------------------------------------------------------
#define OFF_W   4096   // ushorts
#define BUFSZ   8192   // ushorts per buffer (16384 B)

struct Job {
    const ushort *A0; int lda0;
    const ushort *W0; int K0;
    const ushort *A1; int lda1;
    const ushort *W1; int K1;
    const float *bias, *pv, *pc;
    float *c;
    ushort *hdst;
    const ushort *oph;
    float *piadst, *odst;
    int ostride, zc;
};

__global__ __launch_bounds__(512, 6) void lstm_fused3_k(
    Job j0, Job j1, Job j2, int nA, int nAB,
    const float* __restrict__ Wl, const float* __restrict__ blv,
    const float* __restrict__ input)
{
    __shared__ __align__(16) ushort smem[16896];   // 33792 B (2x16KB bufs; Gs [64][132])
    float* Gs = (float*)smem;

    const int tid = threadIdx.x;
    const int lane = tid & 63;
    const int wid = tid >> 6;        // 0..7

    Job j; int bid;
    if ((int)blockIdx.x < nA)       { j = j0; bid = blockIdx.x; }
    else if ((int)blockIdx.x < nAB) { j = j1; bid = blockIdx.x - nA; }
    else                            { j = j2; bid = blockIdx.x - nAB; }

    // 2D XCD-pinned tile mapping: xcd>>2 = m-half, xcd&3 = n-quarter
    const int xcd = bid & 7;
    const int loc = bid >> 3;                         // 0..31
    const int mblk = ((xcd >> 2) << 3) | (loc & 7);   // 0..15
    const int nblk = ((xcd & 3) << 2) | (loc >> 3);   // 0..15
    const int m0 = mblk * 128;
    const int n0 = nblk * 128;

    // ---- prologue: out-projection of previous h (1 row per wave) ----
    if (j.oph != nullptr) {
        int row = bid * 8 + wid;
        int xr = (row >> 1) & 3;
        int colp = ((lane >> 2) * 32) + (((lane & 3) ^ xr) << 3);
        ushort8 hh8 = *(const ushort8*)&j.oph[(size_t)row * NH + colp];
        const float4* wv = (const float4*)(Wl + lane * 8);
        float4 w0 = wv[0], w1 = wv[1];
        float wreg[8] = {w0.x, w0.y, w0.z, w0.w, w1.x, w1.y, w1.z, w1.w};
        float s = 0.f;
        #pragma unroll
        for (int e = 0; e < 8; ++e) s = fmaf(h_to_f(hh8[e]), wreg[e], s);
        #pragma unroll
        for (int off = 32; off > 0; off >>= 1) s += __shfl_down(s, off);
        if (lane == 0) {
            float proj = s + blv[0];
            if (j.odst) j.odst[(size_t)row * j.ostride] = proj;
            if (j.piadst) j.piadst[row] = fabsf(proj) * input[(size_t)row * LDIN + (LDIN - 1)];
        }
    }

    // wave geometry: 4m x 2n, wave tile 32x64
    const int wm = wid >> 1;        // 0..3
    const int wn = wid & 1;         // 0..1
    const int fr = lane & 15;
    const int fg = lane >> 4;
    const int rdsw = (fr >> 1) & 3; // read swizzle (row bases multiple of 16)

    // staging geometry: 512 threads, 1 gll16 per plane (A, W)
    const int srow = tid >> 2;      // 0..127
    const int aslot = tid & 3;

    const int nt0 = j.K0 >> 5;
    const int nt1 = j.K1 >> 5;
    const int NT = nt0 + nt1;

    auto stage = [&](int t, int buf) {
        const ushort *Ap, *Wp;
        int lda_, K_, kt;
        if (t < nt0) { Ap = j.A0; lda_ = j.lda0; K_ = j.K0; kt = t * 32; Wp = j.W0; }
        else         { Ap = j.A1; lda_ = j.lda1; K_ = j.K1; kt = (t - nt0) * 32; Wp = j.W1; }
        char* wb = (char*)smem + buf * 16384 + wid * 1024;
        const size_t acol = (size_t)kt + aslot * 8;
        gll16(&Ap[(size_t)(m0 + srow) * lda_ + acol], wb);
        gll16(&Wp[(size_t)(n0 + srow) * K_ + acol],   wb + 8192);
    };

    f32x4 acc[2][4] = {};
    int cur = 0;

    stage(0, 0);
    if (NT > 1) stage(1, 1);

    for (int t = 0; t < NT; ++t) {
        // counted wait: all but the newest 2 loads (stage t+1)
        if (t + 1 < NT) { asm volatile("s_waitcnt vmcnt(2)" ::: "memory"); }
        else            { asm volatile("s_waitcnt vmcnt(0)" ::: "memory"); }
        __builtin_amdgcn_s_barrier();

        const ushort* bp = smem + cur * BUFSZ;
        half8 ah[2], wv[4];
        #pragma unroll
        for (int im = 0; im < 2; ++im) {
            int off = (wm * 32 + im * 16 + fr) * 32 + ((fg ^ rdsw) << 3);
            ah[im] = *(const half8*)&bp[off];
        }
        #pragma unroll
        for (int in = 0; in < 4; ++in) {
            int off = (wn * 64 + in * 16 + fr) * 32 + ((fg ^ rdsw) << 3);
            wv[in] = *(const half8*)&bp[OFF_W + off];
        }
        #pragma unroll
        for (int im = 0; im < 2; ++im)
            #pragma unroll
            for (int in = 0; in < 4; ++in)
                acc[im][in] = __builtin_amdgcn_mfma_f32_16x16x32_f16(ah[im], wv[in], acc[im][in], 0, 0, 0);

        asm volatile("" ::: "memory");
        __builtin_amdgcn_s_barrier();       // all waves done reading buf[cur]
        asm volatile("" ::: "memory");
        if (t + 2 < NT) stage(t + 2, cur);  // refill the buffer just consumed
        cur ^= 1;
    }

    // ---- epilogue: 2 chunks (im = 0,1), Gs = [64][132] f32 aliased ----
    #pragma unroll
    for (int ch = 0; ch < 2; ++ch) {
        __syncthreads();   // stage-buffer reads (or prev chunk) done
        // stage 1: bias + pia, fragments of chunk ch -> Gs
        {
            int g64 = wm * 16 + fg * 4;               // Gs row base
            int rowl = wm * 32 + ch * 16 + fg * 4;    // global row base
            #pragma unroll
            for (int in = 0; in < 4; ++in) {
                int npl = wn * 64 + in * 16 + fr;
                int np = n0 + npl;
                float bias = j.bias[np];
                float pcv = (j.pc != nullptr) ? j.pc[np] : 0.0f;
                #pragma unroll
                for (int r = 0; r < 4; ++r) {
                    float g = acc[ch][in][r] + bias;
                    if (j.pv != nullptr) g += j.pv[m0 + rowl + r] * pcv;
                    Gs[(g64 + r) * 132 + npl] = g;
                }
            }
        }
        __syncthreads();
        // stage 2: per-cell update (4 cells/thread), coalesced I/O
        {
            int r64 = tid >> 3;                  // 0..63 (Gs row)
            int jq = (tid & 7) * 4;              // j-quad within 32-j block
            int brow = (r64 >> 4) * 32 + ch * 16 + (r64 & 15);
            int jbase = (n0 >> 2) + jq;
            size_t rowb = (size_t)(m0 + brow) * NH;
            size_t idx = rowb + jbase;
            float co[4];
            if (j.zc) {
                co[0] = co[1] = co[2] = co[3] = 0.0f;
            } else {
                float4 c0 = *(const float4*)&j.c[idx];
                co[0] = c0.x; co[1] = c0.y; co[2] = c0.z; co[3] = c0.w;
            }
            float cn[4], hn[4];
            #pragma unroll
            for (int jj = 0; jj < 4; ++jj) {
                float4 gv = *(const float4*)&Gs[r64 * 132 + (jq + jj) * 4];
                float cnv = sigmf(gv.y) * co[jj] + sigmf(gv.x) * tanhf_fast(gv.z);
                cn[jj] = cnv;
                hn[jj] = sigmf(gv.w) * tanhf_fast(cnv);
            }
            float4 cs = {cn[0], cn[1], cn[2], cn[3]};
            *(float4*)&j.c[idx] = cs;
            ushort4v hh;
            #pragma unroll
            for (int e = 0; e < 4; ++e) hh[e] = f2h_bits(hn[e]);
            int xb = (brow >> 1) & 3;
            int colp = (jbase & ~31) | ((((jbase >> 3) & 3) ^ xb) << 3) | (jbase & 7);
            *(ushort4v*)&j.hdst[rowb + colp] = hh;
        }
    }
}

// Standalone out-projection from XOR-permuted fp16 h, optional pia.
__global__ __launch_bounds__(256) void out_proj_hl(const ushort* __restrict__ hsrc,
                                                   const float* __restrict__ Wl,
                                                   const float* __restrict__ blv,
                                                   const float* __restrict__ scaleBase,
                                                   float* __restrict__ piadst,
                                                   float* __restrict__ odst, int ostride)
{
    int wave = threadIdx.x >> 6;
    int lane = threadIdx.x & 63;
    int row = blockIdx.x * 4 + wave;
    int xr = (row >> 1) & 3;
    int colp = ((lane >> 2) * 32) + (((lane & 3) ^ xr) << 3);
    ushort8 hh8 = *(const ushort8*)&hsrc[(size_t)row * NH + colp];
    const float4* wv = (const float4*)(Wl + lane * 8);
    float4 w0 = wv[0], w1 = wv[1];
    float wreg[8] = {w0.x, w0.y, w0.z, w0.w, w1.x, w1.y, w1.z, w1.w};
    float s = 0.f;
    #pragma unroll
    for (int e = 0; e < 8; ++e) s = fmaf(h_to_f(hh8[e]), wreg[e], s);
    #pragma unroll
    for (int off = 32; off > 0; off >>= 1) s += __shfl_down(s, off);
    if (lane == 0) {
        float proj = s + blv[0];
        if (odst) odst[(size_t)row * ostride] = proj;
        if (piadst) piadst[row] = fabsf(proj) * scaleBase[(size_t)row * LDIN + (LDIN - 1)];
    }
}

// Split W[4NH][ldw] into permuted SINGLE fp16 plane, n' = j*4+g, with
// XOR-permuted 8-elem groups within each 32-col K-block.
__global__ __launch_bounds__(256) void split_perm_w_k(const float* __restrict__ W,
                                                      ushort* __restrict__ wout,
                                                      int ldw, int kshift)
{
    int idx = blockIdx.x * 256 + threadIdx.x;
    int K = 1 << kshift;
    int np = idx >> kshift;
    int k = idx & (K - 1);
    int ks = (k & ~31) | ((((k >> 3) & 3) ^ ((np >> 1) & 3)) << 3) | (k & 7);
    int orig = ((np & 3) << 9) | (np >> 2);
    wout[idx] = f2h_bits(W[(size_t)orig * ldw + ks]);
}

// Convert input x to fp16 [b][4096], XOR-permuted groups per 32-block.
__global__ __launch_bounds__(256) void split_x_k(const float* __restrict__ input,
                                                 ushort* __restrict__ xh)
{
    int idx = blockIdx.x * 256 + threadIdx.x;   // over BATCH*XCOLS
    int b = idx >> 12;
    int col = idx & (XCOLS - 1);
    int cs = (col & ~31) | ((((col >> 3) & 3) ^ ((b >> 1) & 3)) << 3) | (col & 7);
    xh[idx] = f2h_bits(input[(size_t)b * LDIN + cs]);
}

__global__ __launch_bounds__(256) void bias_prep_k(const float* __restrict__ bih,
                                                   const float* __restrict__ bhh,
                                                   float* __restrict__ bperm)
{
    int np = blockIdx.x * 256 + threadIdx.x;
    int orig = ((np & 3) << 9) | (np >> 2);
    bperm[np] = bih[orig] + bhh[orig];
}

__global__ __launch_bounds__(256) void pc_prep_k(const float* __restrict__ Wih1,
                                                 float* __restrict__ pc)
{
    int np = blockIdx.x * 256 + threadIdx.x;
    int orig = ((np & 3) << 9) | (np >> 2);
    pc[np] = Wih1[(size_t)orig * (NINP + 1) + NINP];
}

extern "C" void kernel_launch(void* const* d_in, const int* in_sizes, int n_in,
                              void* d_out, int out_size, void* d_ws, size_t ws_size,
                              hipStream_t stream)
{
    const float* input = (const float*)d_in[0];
    const float* Wih_p = (const float*)d_in[1];
    const float* Whh_p = (const float*)d_in[2];
    const float* bih_p = (const float*)d_in[3];
    const float* bhh_p = (const float*)d_in[4];
    const float* Wih1  = (const float*)d_in[5];
    const float* Whh1  = (const float*)d_in[6];
    const float* bih1  = (const float*)d_in[7];
    const float* bhh1  = (const float*)d_in[8];
    const float* Wih2  = (const float*)d_in[9];
    const float* Whh2  = (const float*)d_in[10];
    const float* bih2  = (const float*)d_in[11];
    const float* bhh2  = (const float*)d_in[12];
    const float* Wl    = (const float*)d_in[13];
    const float* bl    = (const float*)d_in[14];
    float* out = (float*)d_out;

    const size_t HC = (size_t)BATCH * NH;       // 1M elems
    char* p = (char*)d_ws;
    auto alloc = [&](size_t bytes) { char* r = p; p += (bytes + 255) & ~(size_t)255; return r; };

    float* c_p = (float*)alloc(HC * 4);
    float* c1  = (float*)alloc(HC * 4);
    float* c2  = (float*)alloc(HC * 4);
    ushort* hps[2]; ushort* h1s[2]; ushort* h2s[2];
    for (int i = 0; i < 2; ++i) hps[i] = (ushort*)alloc(HC * 2);
    for (int i = 0; i < 2; ++i) h1s[i] = (ushort*)alloc(HC * 2);
    for (int i = 0; i < 2; ++i) h2s[i] = (ushort*)alloc(HC * 2);
    float* pias   = (float*)alloc((size_t)T * BATCH * 4);
    ushort* WhhP_h = (ushort*)alloc((size_t)G4 * NH * 2);
    ushort* WihP_h = (ushort*)alloc((size_t)G4 * NINP * 2);
    ushort* Whh1_h = (ushort*)alloc((size_t)G4 * NH * 2);
    ushort* Wih1x_h = (ushort*)alloc((size_t)G4 * NINP * 2);
    ushort* Wih2_h = (ushort*)alloc((size_t)G4 * NH * 2);
    ushort* Whh2_h = (ushort*)alloc((size_t)G4 * NH * 2);
    ushort* xh = (ushort*)alloc((size_t)BATCH * XCOLS * 2);
    float* biasP = (float*)alloc(G4 * 4);
    float* bias1 = (float*)alloc(G4 * 4);
    float* bias2 = (float*)alloc(G4 * 4);
    float* pc1   = (float*)alloc(G4 * 4);

    // prep (no memset: t=0 jobs skip h-segments via K=0 and zero c via zc)
    split_perm_w_k<<<(G4 * NH) / 256, 256, 0, stream>>>(Whh_p, WhhP_h, NH, 9);
    split_perm_w_k<<<(G4 * NINP) / 256, 256, 0, stream>>>(Wih_p, WihP_h, NINP, 6);
    split_perm_w_k<<<(G4 * NH) / 256, 256, 0, stream>>>(Whh1, Whh1_h, NH, 9);
    split_perm_w_k<<<(G4 * NINP) / 256, 256, 0, stream>>>(Wih1, Wih1x_h, NINP + 1, 6);
    split_perm_w_k<<<(G4 * NH) / 256, 256, 0, stream>>>(Wih2, Wih2_h, NH, 9);
    split_perm_w_k<<<(G4 * NH) / 256, 256, 0, stream>>>(Whh2, Whh2_h, NH, 9);
    split_x_k<<<(BATCH * XCOLS) / 256, 256, 0, stream>>>(input, xh);
    bias_prep_k<<<G4 / 256, 256, 0, stream>>>(bih_p, bhh_p, biasP);
    bias_prep_k<<<G4 / 256, 256, 0, stream>>>(bih1, bhh1, bias1);
    bias_prep_k<<<G4 / 256, 256, 0, stream>>>(bih2, bhh2, bias2);
    pc_prep_k<<<G4 / 256, 256, 0, stream>>>(Wih1, pc1);

    auto jobP1 = [&](int s) {
        Job jo = {};
        jo.A0 = xh + (size_t)s * NINP; jo.lda0 = XCOLS;
        jo.W0 = WihP_h; jo.K0 = NINP;
        jo.A1 = hps[s & 1]; jo.lda1 = NH;
        jo.W1 = WhhP_h; jo.K1 = (s == 0) ? 0 : NH;
        jo.bias = biasP; jo.pv = nullptr; jo.pc = nullptr;
        jo.c = c_p; jo.hdst = hps[(s + 1) & 1];
        jo.oph = (s > 0) ? hps[s & 1] : nullptr;
        jo.piadst = (s > 0) ? (pias + (size_t)(s - 1) * BATCH) : nullptr;
        jo.odst = nullptr; jo.ostride = 0; jo.zc = (s == 0);
        return jo;
    };
    auto jobL1 = [&](int t) {
        Job jo = {};
        jo.A0 = xh + (size_t)t * NINP; jo.lda0 = XCOLS;
        jo.W0 = Wih1x_h; jo.K0 = NINP;
        jo.A1 = h1s[t & 1]; jo.lda1 = NH;
        jo.W1 = Whh1_h; jo.K1 = (t == 0) ? 0 : NH;
        jo.bias = bias1; jo.pv = pias + (size_t)t * BATCH; jo.pc = pc1;
        jo.c = c1; jo.hdst = h1s[(t + 1) & 1];
        jo.oph = nullptr;
        jo.piadst = nullptr; jo.odst = nullptr; jo.ostride = 0;
        jo.zc = (t == 0);
        return jo;
    };
    auto jobL2 = [&](int t) {
        Job jo = {};
        jo.A0 = h1s[(t + 1) & 1]; jo.lda0 = NH;
        jo.W0 = Wih2_h; jo.K0 = NH;
        jo.A1 = h2s[t & 1]; jo.lda1 = NH;
        jo.W1 = Whh2_h; jo.K1 = (t == 0) ? 0 : NH;
        jo.bias = bias2; jo.pv = nullptr; jo.pc = nullptr;
        jo.c = c2; jo.hdst = h2s[(t + 1) & 1];
        jo.oph = (t > 0) ? h2s[t & 1] : nullptr;
        jo.piadst = nullptr;
        jo.odst = (t > 0) ? (out + (t - 1)) : nullptr; jo.ostride = T + 1;
        jo.zc = (t == 0);
        return jo;
    };

    // One dispatch per superstep s: [L2(s-3) | L1(s-2) | P1(s)], 3 blocks/CU.
    for (int s = 0; s <= 66; ++s) {
        int nL2 = (s >= 3) ? 256 : 0;
        int nL1 = (s >= 2 && s <= 65) ? 256 : 0;
        int nP1 = (s <= 63) ? 256 : 0;
        Job j0 = {}, j1 = {}, j2 = {};
        if (nL2) j0 = jobL2(s - 3);
        if (nL1) j1 = jobL1(s - 2);
        if (nP1) j2 = jobP1(s);
        int nA = nL2, nAB = nL2 + nL1, total = nL2 + nL1 + nP1;
        lstm_fused3_k<<<total, 512, 0, stream>>>(j0, j1, j2, nA, nAB, Wl, bl, input);
        if (s == 63) {
            // T1: h_p(64) ready -> pias[63] (used by L1(63) at s=65) and raw
            // last_pia column out[:,T].
            out_proj_hl<<<BATCH / 4, 256, 0, stream>>>(hps[0], Wl, bl, input,
                                                       pias + (size_t)63 * BATCH,
                                                       out + T, T + 1);
        }
    }
    // T4: proj h2(64) -> out[:,63].
    out_proj_hl<<<BATCH / 4, 256, 0, stream>>>(h2s[0], Wl, bl, input,
                                               nullptr, out + 63, T + 1);
}